// Round 18
// baseline (81.831 us; speedup 1.0000x reference)
//
#include <hip/hip_runtime.h>
#include <cstdint>
#include <cstddef>

#define BATCH 4
#define CIN   512
#define NPIX  1024
#define HEADS 16
#define DH    32
#define DATTN 512
#define O_QKV 1536

typedef unsigned short u16;
typedef __bf16 bf16x4 __attribute__((ext_vector_type(4)));
typedef __bf16 bf16x8 __attribute__((ext_vector_type(8)));
typedef float  f32x4  __attribute__((ext_vector_type(4)));

typedef const __attribute__((address_space(1))) void g1_t;
typedef __attribute__((address_space(3))) void l3_t;

#if defined(__has_builtin)
#if __has_builtin(__builtin_amdgcn_exp2f)
#define EXP2(x) __builtin_amdgcn_exp2f(x)
#endif
#endif
#ifndef EXP2
#define EXP2(x) __expf((x) * 0.6931471805599453f)
#endif

__device__ __forceinline__ u16 f2bf(float f) {
  unsigned u = __float_as_uint(f);
  u += 0x7fffu + ((u >> 16) & 1u);
  return (u16)(u >> 16);
}

// async global->LDS, 16B per lane; lp must be wave-uniform (HW: base + lane*16)
__device__ __forceinline__ void gl_lds16(const void* gp, void* lp) {
  __builtin_amdgcn_global_load_lds((g1_t*)gp, (l3_t*)lp, 16, 0, 0);
}

// ---------------------------------------------------------------------------
// prep_fused: blocks 0..511 = x [B][C][N] f32 -> xt [B][N][C] bf16 (LDS
// transpose); blocks 512..1535 = w_qkv + w_proj f32 -> bf16. One launch.
// ---------------------------------------------------------------------------
__global__ __launch_bounds__(256) void prep_fused(const float* __restrict__ x,
                                                  const float* __restrict__ w1,
                                                  const float* __restrict__ w2,
                                                  u16* __restrict__ xt,
                                                  u16* __restrict__ o1,
                                                  u16* __restrict__ o2) {
  const int t = threadIdx.x;
  if (blockIdx.x < 512) {
    __shared__ float sT[64][65];
    const int q  = blockIdx.x;
    const int n0 = (q & 15) << 6;
    const int c0 = ((q >> 4) & 7) << 6;
    const int b  = q >> 7;
    const float* xb = x + ((size_t)b * CIN + c0) * NPIX + n0;
#pragma unroll
    for (int i = 0; i < 4; ++i) {
      int r   = i * 16 + (t >> 4);
      int col = (t & 15) << 2;
      float4 v = *reinterpret_cast<const float4*>(&xb[(size_t)r * NPIX + col]);
      sT[r][col + 0] = v.x; sT[r][col + 1] = v.y;
      sT[r][col + 2] = v.z; sT[r][col + 3] = v.w;
    }
    __syncthreads();
#pragma unroll
    for (int i = 0; i < 2; ++i) {
      int nl = t >> 2;
      int ch = (t & 3) + (i << 2);
      u16 tmp[8];
#pragma unroll
      for (int e = 0; e < 8; ++e) tmp[e] = f2bf(sT[(ch << 3) + e][nl]);
      *reinterpret_cast<uint4*>(&xt[((size_t)b * NPIX + n0 + nl) * CIN + c0 + (ch << 3)]) =
          *reinterpret_cast<uint4*>(tmp);
    }
  } else {
    const int idx = (blockIdx.x - 512) * 256 + t;   // float4 index
    const int n1 = (O_QKV * CIN) >> 2;              // 196608
    float4 v = (idx < n1) ? reinterpret_cast<const float4*>(w1)[idx]
                          : reinterpret_cast<const float4*>(w2)[idx - n1];
    uint2 pk = make_uint2((unsigned)f2bf(v.x) | ((unsigned)f2bf(v.y) << 16),
                          (unsigned)f2bf(v.z) | ((unsigned)f2bf(v.w) << 16));
    if (idx < n1) reinterpret_cast<uint2*>(o1)[idx] = pk;
    else          reinterpret_cast<uint2*>(o2)[idx - n1] = pk;
  }
}

// ---------------------------------------------------------------------------
// QKV GEMM (MFMA) + FUSED rel->bf16 conversion (extra blocks, same launch).
// bx < 8: GEMM block (M-tile=96 = one head, N-tile=128, BK=64, 4 waves).
// bx >= 8: rel conversion chunk c = (bx-8) + 32*(by + 16*bz) in [0,2048):
//   8192 f32 per chunk; relL[i] = bf16(rel[i] * log2e). Conversion rides
//   alongside the compute-bound GEMM (3.6% HBM) -> nearly free.
// GEMM epilogue: +bias, bf16; q PRE-SCALED by scale*log2e.
// qt/kt [b][h][n][32], vt [b][h][d][n].
// ---------------------------------------------------------------------------
__global__ __launch_bounds__(256) void gemm_qkv_mfma(const u16* __restrict__ wq,
                                                     const u16* __restrict__ xt,
                                                     const float* __restrict__ bias,
                                                     const float* __restrict__ rel,
                                                     u16* __restrict__ qt,
                                                     u16* __restrict__ kt,
                                                     u16* __restrict__ vt,
                                                     u16* __restrict__ relL) {
  const int t = threadIdx.x;

  if (blockIdx.x >= 8) {
    // ---- rel -> bf16 (pre-multiplied by log2e) ----
    const float LOG2E = 1.4426950408889634f;
    const int c = (blockIdx.x - 8) + 32 * (blockIdx.y + 16 * blockIdx.z);
    const size_t base = (size_t)c * 8192 + (size_t)t * 32;
#pragma unroll
    for (int i = 0; i < 4; ++i) {
      f32x4 a = *reinterpret_cast<const f32x4*>(rel + base + i * 8);
      f32x4 b4 = *reinterpret_cast<const f32x4*>(rel + base + i * 8 + 4);
      u16 tmp[8];
      tmp[0] = f2bf(a[0] * LOG2E);  tmp[1] = f2bf(a[1] * LOG2E);
      tmp[2] = f2bf(a[2] * LOG2E);  tmp[3] = f2bf(a[3] * LOG2E);
      tmp[4] = f2bf(b4[0] * LOG2E); tmp[5] = f2bf(b4[1] * LOG2E);
      tmp[6] = f2bf(b4[2] * LOG2E); tmp[7] = f2bf(b4[3] * LOG2E);
      *reinterpret_cast<uint4*>(relL + base + i * 8) = *reinterpret_cast<uint4*>(tmp);
    }
    return;
  }

  __shared__ __align__(16) u16 sA[96 * 64];
  __shared__ __align__(16) u16 sB[128 * 64];
  const int w  = t >> 6, l = t & 63, g = l >> 4, ln = l & 15;
  const int n0 = blockIdx.x * 128;
  const int h  = blockIdx.y;
  const int b  = blockIdx.z;
  const int wm = w >> 1, wn = w & 1;

  const u16* wbase = wq + (size_t)h * 96 * CIN;
  const u16* xbase = xt + ((size_t)b * NPIX + n0) * CIN;

  f32x4 acc[3][4];
#pragma unroll
  for (int mi = 0; mi < 3; ++mi)
#pragma unroll
    for (int ni = 0; ni < 4; ++ni) acc[mi][ni] = {0.f, 0.f, 0.f, 0.f};

  for (int k0 = 0; k0 < CIN; k0 += 64) {
#pragma unroll
    for (int i = 0; i < 3; ++i) {
      int chunk = i * 256 + (w << 6) + l;
      gl_lds16(wbase + ((size_t)(chunk >> 3)) * CIN + k0 + ((chunk & 7) << 3),
               (char*)sA + i * 4096 + (w << 10));
    }
#pragma unroll
    for (int i = 0; i < 4; ++i) {
      int chunk = i * 256 + (w << 6) + l;
      gl_lds16(xbase + ((size_t)(chunk >> 3)) * CIN + k0 + ((chunk & 7) << 3),
               (char*)sB + i * 4096 + (w << 10));
    }
    __syncthreads();
#pragma unroll
    for (int kk = 0; kk < 64; kk += 32) {
      bf16x8 af[3], bfr[4];
#pragma unroll
      for (int mi = 0; mi < 3; ++mi)
        af[mi] = *reinterpret_cast<const bf16x8*>(&sA[(48 * wm + 16 * mi + ln) * 64 + kk + (g << 3)]);
#pragma unroll
      for (int ni = 0; ni < 4; ++ni)
        bfr[ni] = *reinterpret_cast<const bf16x8*>(&sB[((wn << 6) + (ni << 4) + ln) * 64 + kk + (g << 3)]);
#pragma unroll
      for (int mi = 0; mi < 3; ++mi)
#pragma unroll
        for (int ni = 0; ni < 4; ++ni)
          acc[mi][ni] = __builtin_amdgcn_mfma_f32_16x16x32_bf16(af[mi], bfr[ni], acc[mi][ni], 0, 0, 0);
    }
    __syncthreads();
  }

  const float QSC = 0.17677669529663687f * 1.4426950408889634f;  // scale*log2e
  const float* bh = bias + h * 96;
#pragma unroll
  for (int mi = 0; mi < 3; ++mi) {
    const int sec = 48 * wm + 16 * mi;
    const int rb  = sec + (g << 2);
    const float b0 = bh[rb + 0], b1 = bh[rb + 1], b2 = bh[rb + 2], b3 = bh[rb + 3];
#pragma unroll
    for (int ni = 0; ni < 4; ++ni) {
      const int n = n0 + (wn << 6) + (ni << 4) + ln;
      f32x4 a = acc[mi][ni];
      float v0 = a[0] + b0, v1 = a[1] + b1, v2 = a[2] + b2, v3 = a[3] + b3;
      if (sec < 32) { v0 *= QSC; v1 *= QSC; v2 *= QSC; v3 *= QSC; }
      u16 e0 = f2bf(v0), e1 = f2bf(v1), e2 = f2bf(v2), e3 = f2bf(v3);
      if (sec < 32) {
        const int d = sec + (g << 2);
        uint2 pk = make_uint2((unsigned)e0 | ((unsigned)e1 << 16),
                              (unsigned)e2 | ((unsigned)e3 << 16));
        *reinterpret_cast<uint2*>(&qt[(((size_t)(b * HEADS + h)) * NPIX + n) * DH + d]) = pk;
      } else if (sec < 64) {
        const int d = sec - 32 + (g << 2);
        uint2 pk = make_uint2((unsigned)e0 | ((unsigned)e1 << 16),
                              (unsigned)e2 | ((unsigned)e3 << 16));
        *reinterpret_cast<uint2*>(&kt[(((size_t)(b * HEADS + h)) * NPIX + n) * DH + d]) = pk;
      } else {
        const int d = sec - 64 + (g << 2);
        u16* vp = &vt[(((size_t)(b * HEADS + h)) * DH + d) * NPIX + n];
        vp[0] = e0; vp[NPIX] = e1; vp[2 * NPIX] = e2; vp[3 * NPIX] = e3;
      }
    }
  }
}

// ---------------------------------------------------------------------------
// MFMA flash attention v18 = r17 (KVBLK=128) with BF16 rel (log2e pre-folded).
// Theory: every 41-47us variant shared an unchanged 256MB/dispatch logical
// rel f32 stream (~6 TB/s through L2/L3 = the plateau). bf16 rel halves rel
// bytes at every cache level and halves rel load count.
// rel loads: uint2 (bf16x4, 8B) per (half,v); expand via shift; exp arg =
// S' + relL (add; log2e folded at conversion).
// Rest identical to r17: 8 j-steps of 128, one barrier/step, K/V dbuf LDS
// (r10 swizzles per 64-half), sP per wave, grid 1024 XCD decode, (256,4).
// ---------------------------------------------------------------------------
__global__ __launch_bounds__(256, 4) void attn_mfma(const u16* __restrict__ qt,
                                                    const u16* __restrict__ kt,
                                                    const u16* __restrict__ vt,
                                                    const u16* __restrict__ relL,
                                                    u16* __restrict__ aout) {
  __shared__ __align__(16) u16 sK[2][4096];      // [buf][2half x 32r x 8slot x 8] 16KB
  __shared__ __align__(16) u16 sV[2][4096];      // [buf][2half x 32d x 8slot x 8] 16KB
  __shared__ __align__(16) u16 sP[4][2048];      // per-wave [2half][16][8slot][8] 16KB

  const int t  = threadIdx.x;
  const int w  = t >> 6, l = t & 63, g = l >> 4, ln = l & 15;
  const int bid = blockIdx.x;
  const int xcd = bid & 7, sl = bid >> 3;   // sl 0..127
  const int b   = sl & 3;
  const int i0  = ((sl >> 2) & 15) << 6;
  const int h   = (xcd << 1) | (sl >> 6);
  const int iw  = w;                        // i-segment (16 rows)

  const size_t bh = (size_t)(b * HEADS + h);

  // staging (r10 mapping per 64-wide half): thread t stages chunk t of each
  // half. c=t -> r=c>>3, slot=c&7; sources pre-swizzled.
  const int sc_r  = t >> 3;
  const int sc_kc = (t & 7) ^ (sc_r & 7) ^ ((sc_r >> 3) & 1);
  const int sc_vc = (t & 7) ^ (sc_r & 7);
  const u16* ksrc = kt + (bh * NPIX + ((sc_r << 1) | (sc_kc >> 2))) * DH +
                    ((sc_kc & 3) << 3);
  const u16* vsrc = vt + (bh * DH + sc_r) * NPIX + (sc_vc << 3);
  char* kdst = (char*)&sK[0][0] + (w << 10);
  char* vdst = (char*)&sV[0][0] + (w << 10);

  // step s covers j in [s*128, s*128+128); half hh at +hh*64.
#define STAGE(s_, p_) do {                                                  \
    gl_lds16(ksrc + (size_t)(s_) * 4096,        kdst + (p_) * 8192);        \
    gl_lds16(ksrc + (size_t)(s_) * 4096 + 2048, kdst + (p_) * 8192 + 4096); \
    gl_lds16(vsrc + (size_t)(s_) * 128,         vdst + (p_) * 8192);        \
    gl_lds16(vsrc + (size_t)(s_) * 128 + 64,    vdst + (p_) * 8192 + 4096); \
  } while (0)

  STAGE(0, 0);

  // Q fragment (pre-scaled by scale*log2e): lane -> row i0+16*iw+ln, k=8g..+8
  bf16x8 qf = *reinterpret_cast<const bf16x8*>(
      qt + (bh * NPIX + i0 + (iw << 4) + ln) * DH + (g << 3));

  // relL (bf16, *log2e): rows i0+16iw+4g+v, cols s*128 + hh*64 + 4ln + (0..3)
  const u16* relp = relL + ((size_t)h * NPIX + i0 + (iw << 4) + (g << 2)) * NPIX +
                    (ln << 2);

  f32x4 vzero = {0.f, 0.f, 0.f, 0.f};
  f32x4 accO[2] = {vzero, vzero};
  f32x4 l_lane = vzero;

  u16* sPw = &sP[w][0];

  for (int s = 0; s < 8; ++s) {
    const int p = s & 1;
    __syncthreads();                        // buf p staged; buf p^1 free
    if (s < 7) STAGE(s + 1, p ^ 1);

    // rel loads for this step (bf16x4 as uint2; expanded after QK)
    uint2 relq[2][4];
#pragma unroll
    for (int hh = 0; hh < 2; ++hh)
#pragma unroll
      for (int v = 0; v < 4; ++v)
        relq[hh][v] = *reinterpret_cast<const uint2*>(
            relp + (size_t)v * NPIX + (s << 7) + (hh << 6));

    const u16* Kb = &sK[p][0];
    const u16* Vb = &sV[p][0];

    // ---- S' = Q'^T K: 8 fragments; frag (hh,q) covers j = 64hh + 4ln + q ----
    f32x4 sfr[8];
    __builtin_amdgcn_s_setprio(1);
#pragma unroll
    for (int jj = 0; jj < 8; ++jj) {
      const int hh = jj >> 2, q = jj & 3;
      const int r  = (ln << 1) + (q >> 1);
      const int ks = ((((q & 1) << 2) | g) ^ (r & 7)) ^ ((r >> 3) & 1);
      bf16x8 kf = *reinterpret_cast<const bf16x8*>(Kb + (hh << 11) + r * 64 + ks * 8);
      sfr[jj] = __builtin_amdgcn_mfma_f32_16x16x32_bf16(qf, kf, vzero, 0, 0, 0);
    }
    __builtin_amdgcn_s_setprio(0);

    // ---- P = exp2(S' + relL); swizzled b64 write per row per half ----
#pragma unroll
    for (int v = 0; v < 4; ++v) {
      const int rw = (g << 2) + v;
      const int pwoff = rw * 64 + ((((ln >> 1) ^ (rw & 7)) << 3) | ((ln & 1) << 2));
      {
        const uint2 rq = relq[0][v];
        float r0 = __uint_as_float((rq.x & 0xffffu) << 16);
        float r1 = __uint_as_float(rq.x & 0xffff0000u);
        float r2 = __uint_as_float((rq.y & 0xffffu) << 16);
        float r3 = __uint_as_float(rq.y & 0xffff0000u);
        float p0 = EXP2(r0 + sfr[0][v]);
        float p1 = EXP2(r1 + sfr[1][v]);
        float p2 = EXP2(r2 + sfr[2][v]);
        float p3 = EXP2(r3 + sfr[3][v]);
        l_lane[v] += (p0 + p1) + (p2 + p3);
        bf16x4 pk;
        pk[0] = (__bf16)p0; pk[1] = (__bf16)p1; pk[2] = (__bf16)p2; pk[3] = (__bf16)p3;
        *reinterpret_cast<bf16x4*>(sPw + pwoff) = pk;
      }
      {
        const uint2 rq = relq[1][v];
        float r0 = __uint_as_float((rq.x & 0xffffu) << 16);
        float r1 = __uint_as_float(rq.x & 0xffff0000u);
        float r2 = __uint_as_float((rq.y & 0xffffu) << 16);
        float r3 = __uint_as_float(rq.y & 0xffff0000u);
        float p4 = EXP2(r0 + sfr[4][v]);
        float p5 = EXP2(r1 + sfr[5][v]);
        float p6 = EXP2(r2 + sfr[6][v]);
        float p7 = EXP2(r3 + sfr[7][v]);
        l_lane[v] += (p4 + p5) + (p6 + p7);
        bf16x4 pk2;
        pk2[0] = (__bf16)p4; pk2[1] = (__bf16)p5; pk2[2] = (__bf16)p6; pk2[3] = (__bf16)p7;
        *reinterpret_cast<bf16x4*>(sPw + 1024 + pwoff) = pk2;
      }
    }

    // ---- PV: 4 k-chunks of 32 (c: hh=c>>1, kc2=c&1) x 2 d-halves ----
    __builtin_amdgcn_s_setprio(1);
#pragma unroll
    for (int c = 0; c < 4; ++c) {
      const int hh = c >> 1, kc2 = c & 1;
      const int lc = (kc2 << 2) | g;
      bf16x8 pa = *reinterpret_cast<const bf16x8*>(
          sPw + (hh << 10) + ln * 64 + ((lc ^ (ln & 7)) << 3));
#pragma unroll
      for (int dc = 0; dc < 2; ++dc) {
        const int d  = (dc << 4) + ln;
        const int vs = lc ^ (d & 7);
        bf16x8 vf = *reinterpret_cast<const bf16x8*>(Vb + (hh << 11) + d * 64 + vs * 8);
        accO[dc] = __builtin_amdgcn_mfma_f32_16x16x32_bf16(pa, vf, accO[dc], 0, 0, 0);
      }
    }
    __builtin_amdgcn_s_setprio(0);
  }
#undef STAGE

  // ---- epilogue: shuffle-reduce l, divide, bf16 write [b][n][c] ----
#pragma unroll
  for (int v = 0; v < 4; ++v) {
    float ls = l_lane[v];
    ls += __shfl_xor(ls, 1);
    ls += __shfl_xor(ls, 2);
    ls += __shfl_xor(ls, 4);
    ls += __shfl_xor(ls, 8);
    const float inv = 1.f / ls;
    const size_t row = (size_t)b * NPIX + i0 + (iw << 4) + (g << 2) + v;
    aout[row * DATTN + (h << 5) + ln]      = f2bf(accO[0][v] * inv);
    aout[row * DATTN + (h << 5) + 16 + ln] = f2bf(accO[1][v] * inv);
  }
}

// ---------------------------------------------------------------------------
// Proj GEMM (MFMA): out[b][o][n] = sum_k Wp[o,k] * A[b][n][k] + bias[o], f32 out.
// ---------------------------------------------------------------------------
__global__ __launch_bounds__(256) void gemm_proj_mfma(const u16* __restrict__ wp,
                                                      const u16* __restrict__ at,
                                                      const float* __restrict__ bias,
                                                      float* __restrict__ out) {
  __shared__ __align__(16) u16 sA[64 * 64];
  __shared__ __align__(16) u16 sB[128 * 64];
  const int t  = threadIdx.x;
  const int w  = t >> 6, l = t & 63, g = l >> 4, ln = l & 15;
  const int n0 = blockIdx.x * 128;
  const int o0 = blockIdx.y * 64;
  const int b  = blockIdx.z;
  const int wm = w >> 1, wn = w & 1;

  const u16* wbase = wp + (size_t)o0 * DATTN;
  const u16* abase = at + ((size_t)b * NPIX + n0) * DATTN;

  f32x4 acc[2][4];
#pragma unroll
  for (int mi = 0; mi < 2; ++mi)
#pragma unroll
    for (int ni = 0; ni < 4; ++ni) acc[mi][ni] = {0.f, 0.f, 0.f, 0.f};

  for (int k0 = 0; k0 < DATTN; k0 += 64) {
#pragma unroll
    for (int i = 0; i < 2; ++i) {
      int chunk = i * 256 + (w << 6) + l;
      gl_lds16(wbase + ((size_t)(chunk >> 3)) * DATTN + k0 + ((chunk & 7) << 3),
               (char*)sA + i * 4096 + (w << 10));
    }
#pragma unroll
    for (int i = 0; i < 4; ++i) {
      int chunk = i * 256 + (w << 6) + l;
      gl_lds16(abase + ((size_t)(chunk >> 3)) * DATTN + k0 + ((chunk & 7) << 3),
               (char*)sB + i * 4096 + (w << 10));
    }
    __syncthreads();
#pragma unroll
    for (int kk = 0; kk < 64; kk += 32) {
      bf16x8 af[2], bfr[4];
#pragma unroll
      for (int mi = 0; mi < 2; ++mi)
        af[mi] = *reinterpret_cast<const bf16x8*>(&sA[((wm << 5) + (mi << 4) + ln) * 64 + kk + (g << 3)]);
#pragma unroll
      for (int ni = 0; ni < 4; ++ni)
        bfr[ni] = *reinterpret_cast<const bf16x8*>(&sB[((wn << 6) + (ni << 4) + ln) * 64 + kk + (g << 3)]);
#pragma unroll
      for (int mi = 0; mi < 2; ++mi)
#pragma unroll
        for (int ni = 0; ni < 4; ++ni)
          acc[mi][ni] = __builtin_amdgcn_mfma_f32_16x16x32_bf16(af[mi], bfr[ni], acc[mi][ni], 0, 0, 0);
    }
    __syncthreads();
  }

#pragma unroll
  for (int mi = 0; mi < 2; ++mi) {
    const int o = o0 + (wm << 5) + (mi << 4) + (g << 2);
    const float b0 = bias[o], b1 = bias[o + 1], b2 = bias[o + 2], b3 = bias[o + 3];
#pragma unroll
    for (int ni = 0; ni < 4; ++ni) {
      const int n = n0 + (wn << 6) + (ni << 4) + ln;
      float* op = &out[((size_t)b * DATTN + o) * NPIX + n];
      op[0]        = acc[mi][ni][0] + b0;
      op[NPIX]     = acc[mi][ni][1] + b1;
      op[2 * NPIX] = acc[mi][ni][2] + b2;
      op[3 * NPIX] = acc[mi][ni][3] + b3;
    }
  }
}

extern "C" void kernel_launch(void* const* d_in, const int* in_sizes, int n_in,
                              void* d_out, int out_size, void* d_ws, size_t ws_size,
                              hipStream_t stream) {
  (void)in_sizes; (void)n_in; (void)out_size; (void)ws_size;
  const float* x      = (const float*)d_in[0];
  const float* w_qkv  = (const float*)d_in[1];
  const float* b_qkv  = (const float*)d_in[2];
  const float* w_proj = (const float*)d_in[3];
  const float* b_proj = (const float*)d_in[4];
  const float* rel    = (const float*)d_in[5];
  float* out = (float*)d_out;

  u16* xt    = (u16*)d_ws;                                   // 4 MB
  u16* wq_bf = xt + (size_t)BATCH * NPIX * CIN;              // 1.5 MB
  u16* wp_bf = wq_bf + (size_t)O_QKV * CIN;                  // 0.5 MB
  u16* qt    = wp_bf + (size_t)DATTN * DATTN;                // 4 MB
  u16* kt    = qt + (size_t)BATCH * HEADS * NPIX * DH;       // 4 MB
  u16* vt    = kt + (size_t)BATCH * HEADS * NPIX * DH;       // 4 MB
  u16* aout  = vt + (size_t)BATCH * HEADS * NPIX * DH;       // 4 MB
  u16* relL  = aout + (size_t)BATCH * NPIX * DATTN;          // 33.5 MB

  prep_fused<<<1536, 256, 0, stream>>>(x, w_qkv, w_proj, xt, wq_bf, wp_bf);
  gemm_qkv_mfma<<<dim3(40, HEADS, BATCH), 256, 0, stream>>>(wq_bf, xt, b_qkv, rel,
                                                            qt, kt, vt, relL);
  attn_mfma<<<1024, 256, 0, stream>>>(qt, kt, vt, relL, aout);
  gemm_proj_mfma<<<dim3(NPIX / 128, DATTN / 64, BATCH), 256, 0, stream>>>(wp_bf, aout, b_proj, out);
}

// Round 19
// 78.693 us; speedup vs baseline: 1.0399x; 1.0399x over previous
//
#include <hip/hip_runtime.h>
#include <cstdint>
#include <cstddef>

#define BATCH 4
#define CIN   512
#define NPIX  1024
#define HEADS 16
#define DH    32
#define DATTN 512
#define O_QKV 1536

typedef unsigned short u16;
typedef __bf16 bf16x4 __attribute__((ext_vector_type(4)));
typedef __bf16 bf16x8 __attribute__((ext_vector_type(8)));
typedef float  f32x4  __attribute__((ext_vector_type(4)));

typedef const __attribute__((address_space(1))) void g1_t;
typedef __attribute__((address_space(3))) void l3_t;

#if defined(__has_builtin)
#if __has_builtin(__builtin_amdgcn_exp2f)
#define EXP2(x) __builtin_amdgcn_exp2f(x)
#endif
#endif
#ifndef EXP2
#define EXP2(x) __expf((x) * 0.6931471805599453f)
#endif

__device__ __forceinline__ u16 f2bf(float f) {
  unsigned u = __float_as_uint(f);
  u += 0x7fffu + ((u >> 16) & 1u);
  return (u16)(u >> 16);
}

// async global->LDS, 16B per lane; lp must be wave-uniform (HW: base + lane*16)
__device__ __forceinline__ void gl_lds16(const void* gp, void* lp) {
  __builtin_amdgcn_global_load_lds((g1_t*)gp, (l3_t*)lp, 16, 0, 0);
}

// ---------------------------------------------------------------------------
// prep_fused: blocks 0..511 = x [B][C][N] f32 -> xt [B][N][C] bf16 (LDS
// transpose); blocks 512..1535 = w_qkv + w_proj f32 -> bf16. One launch.
// ---------------------------------------------------------------------------
__global__ __launch_bounds__(256) void prep_fused(const float* __restrict__ x,
                                                  const float* __restrict__ w1,
                                                  const float* __restrict__ w2,
                                                  u16* __restrict__ xt,
                                                  u16* __restrict__ o1,
                                                  u16* __restrict__ o2) {
  const int t = threadIdx.x;
  if (blockIdx.x < 512) {
    __shared__ float sT[64][65];
    const int q  = blockIdx.x;
    const int n0 = (q & 15) << 6;
    const int c0 = ((q >> 4) & 7) << 6;
    const int b  = q >> 7;
    const float* xb = x + ((size_t)b * CIN + c0) * NPIX + n0;
#pragma unroll
    for (int i = 0; i < 4; ++i) {
      int r   = i * 16 + (t >> 4);
      int col = (t & 15) << 2;
      float4 v = *reinterpret_cast<const float4*>(&xb[(size_t)r * NPIX + col]);
      sT[r][col + 0] = v.x; sT[r][col + 1] = v.y;
      sT[r][col + 2] = v.z; sT[r][col + 3] = v.w;
    }
    __syncthreads();
#pragma unroll
    for (int i = 0; i < 2; ++i) {
      int nl = t >> 2;
      int ch = (t & 3) + (i << 2);
      u16 tmp[8];
#pragma unroll
      for (int e = 0; e < 8; ++e) tmp[e] = f2bf(sT[(ch << 3) + e][nl]);
      *reinterpret_cast<uint4*>(&xt[((size_t)b * NPIX + n0 + nl) * CIN + c0 + (ch << 3)]) =
          *reinterpret_cast<uint4*>(tmp);
    }
  } else {
    const int idx = (blockIdx.x - 512) * 256 + t;   // float4 index
    const int n1 = (O_QKV * CIN) >> 2;              // 196608
    float4 v = (idx < n1) ? reinterpret_cast<const float4*>(w1)[idx]
                          : reinterpret_cast<const float4*>(w2)[idx - n1];
    uint2 pk = make_uint2((unsigned)f2bf(v.x) | ((unsigned)f2bf(v.y) << 16),
                          (unsigned)f2bf(v.z) | ((unsigned)f2bf(v.w) << 16));
    if (idx < n1) reinterpret_cast<uint2*>(o1)[idx] = pk;
    else          reinterpret_cast<uint2*>(o2)[idx - n1] = pk;
  }
}

// ---------------------------------------------------------------------------
// QKV GEMM (MFMA) + FUSED rel->bf16 conversion (extra blocks, same launch).
// bx < 32: rel conversion chunk c = bx + 32*(by + 16*bz) in [0,2048):
//   8192 f32/chunk; COALESCED: thread t, iter i handles 8 floats at
//   (i*256+t)*8 -> adjacent lanes 32B apart (wave = 2KB contiguous runs).
//   relL[i] = bf16(rel[i] * log2e). Conversion blocks dispatch FIRST so the
//   HBM stream runs under the compute-bound GEMM blocks.
// bx >= 32: GEMM block (M-tile=96 = one head, N-tile=128, BK=64, 4 waves).
// GEMM epilogue: +bias, bf16; q PRE-SCALED by scale*log2e.
// qt/kt [b][h][n][32], vt [b][h][d][n].
// ---------------------------------------------------------------------------
__global__ __launch_bounds__(256) void gemm_qkv_mfma(const u16* __restrict__ wq,
                                                     const u16* __restrict__ xt,
                                                     const float* __restrict__ bias,
                                                     const float* __restrict__ rel,
                                                     u16* __restrict__ qt,
                                                     u16* __restrict__ kt,
                                                     u16* __restrict__ vt,
                                                     u16* __restrict__ relL) {
  const int t = threadIdx.x;

  if (blockIdx.x < 32) {
    // ---- rel -> bf16 (pre-multiplied by log2e), coalesced ----
    const float LOG2E = 1.4426950408889634f;
    const int c = blockIdx.x + 32 * (blockIdx.y + 16 * (int)blockIdx.z);
    const size_t cbase = (size_t)c * 8192;
#pragma unroll
    for (int i = 0; i < 4; ++i) {
      const size_t off = cbase + ((size_t)(i * 256 + t)) * 8;
      f32x4 a  = *reinterpret_cast<const f32x4*>(rel + off);
      f32x4 b4 = *reinterpret_cast<const f32x4*>(rel + off + 4);
      u16 tmp[8];
      tmp[0] = f2bf(a[0] * LOG2E);  tmp[1] = f2bf(a[1] * LOG2E);
      tmp[2] = f2bf(a[2] * LOG2E);  tmp[3] = f2bf(a[3] * LOG2E);
      tmp[4] = f2bf(b4[0] * LOG2E); tmp[5] = f2bf(b4[1] * LOG2E);
      tmp[6] = f2bf(b4[2] * LOG2E); tmp[7] = f2bf(b4[3] * LOG2E);
      *reinterpret_cast<uint4*>(relL + off) = *reinterpret_cast<uint4*>(tmp);
    }
    return;
  }

  __shared__ __align__(16) u16 sA[96 * 64];
  __shared__ __align__(16) u16 sB[128 * 64];
  const int w  = t >> 6, l = t & 63, g = l >> 4, ln = l & 15;
  const int n0 = (blockIdx.x - 32) * 128;
  const int h  = blockIdx.y;
  const int b  = blockIdx.z;
  const int wm = w >> 1, wn = w & 1;

  const u16* wbase = wq + (size_t)h * 96 * CIN;
  const u16* xbase = xt + ((size_t)b * NPIX + n0) * CIN;

  f32x4 acc[3][4];
#pragma unroll
  for (int mi = 0; mi < 3; ++mi)
#pragma unroll
    for (int ni = 0; ni < 4; ++ni) acc[mi][ni] = {0.f, 0.f, 0.f, 0.f};

  for (int k0 = 0; k0 < CIN; k0 += 64) {
#pragma unroll
    for (int i = 0; i < 3; ++i) {
      int chunk = i * 256 + (w << 6) + l;
      gl_lds16(wbase + ((size_t)(chunk >> 3)) * CIN + k0 + ((chunk & 7) << 3),
               (char*)sA + i * 4096 + (w << 10));
    }
#pragma unroll
    for (int i = 0; i < 4; ++i) {
      int chunk = i * 256 + (w << 6) + l;
      gl_lds16(xbase + ((size_t)(chunk >> 3)) * CIN + k0 + ((chunk & 7) << 3),
               (char*)sB + i * 4096 + (w << 10));
    }
    __syncthreads();
#pragma unroll
    for (int kk = 0; kk < 64; kk += 32) {
      bf16x8 af[3], bfr[4];
#pragma unroll
      for (int mi = 0; mi < 3; ++mi)
        af[mi] = *reinterpret_cast<const bf16x8*>(&sA[(48 * wm + 16 * mi + ln) * 64 + kk + (g << 3)]);
#pragma unroll
      for (int ni = 0; ni < 4; ++ni)
        bfr[ni] = *reinterpret_cast<const bf16x8*>(&sB[((wn << 6) + (ni << 4) + ln) * 64 + kk + (g << 3)]);
#pragma unroll
      for (int mi = 0; mi < 3; ++mi)
#pragma unroll
        for (int ni = 0; ni < 4; ++ni)
          acc[mi][ni] = __builtin_amdgcn_mfma_f32_16x16x32_bf16(af[mi], bfr[ni], acc[mi][ni], 0, 0, 0);
    }
    __syncthreads();
  }

  const float QSC = 0.17677669529663687f * 1.4426950408889634f;  // scale*log2e
  const float* bh = bias + h * 96;
#pragma unroll
  for (int mi = 0; mi < 3; ++mi) {
    const int sec = 48 * wm + 16 * mi;
    const int rb  = sec + (g << 2);
    const float b0 = bh[rb + 0], b1 = bh[rb + 1], b2 = bh[rb + 2], b3 = bh[rb + 3];
#pragma unroll
    for (int ni = 0; ni < 4; ++ni) {
      const int n = n0 + (wn << 6) + (ni << 4) + ln;
      f32x4 a = acc[mi][ni];
      float v0 = a[0] + b0, v1 = a[1] + b1, v2 = a[2] + b2, v3 = a[3] + b3;
      if (sec < 32) { v0 *= QSC; v1 *= QSC; v2 *= QSC; v3 *= QSC; }
      u16 e0 = f2bf(v0), e1 = f2bf(v1), e2 = f2bf(v2), e3 = f2bf(v3);
      if (sec < 32) {
        const int d = sec + (g << 2);
        uint2 pk = make_uint2((unsigned)e0 | ((unsigned)e1 << 16),
                              (unsigned)e2 | ((unsigned)e3 << 16));
        *reinterpret_cast<uint2*>(&qt[(((size_t)(b * HEADS + h)) * NPIX + n) * DH + d]) = pk;
      } else if (sec < 64) {
        const int d = sec - 32 + (g << 2);
        uint2 pk = make_uint2((unsigned)e0 | ((unsigned)e1 << 16),
                              (unsigned)e2 | ((unsigned)e3 << 16));
        *reinterpret_cast<uint2*>(&kt[(((size_t)(b * HEADS + h)) * NPIX + n) * DH + d]) = pk;
      } else {
        const int d = sec - 64 + (g << 2);
        u16* vp = &vt[(((size_t)(b * HEADS + h)) * DH + d) * NPIX + n];
        vp[0] = e0; vp[NPIX] = e1; vp[2 * NPIX] = e2; vp[3 * NPIX] = e3;
      }
    }
  }
}

// ---------------------------------------------------------------------------
// MFMA flash attention v19 = r18 (KVBLK=128, bf16 rel with log2e pre-folded).
// rel loads: uint2 (bf16x4, 8B) per (half,v); expand via shift; exp arg =
// S' + relL. 8 j-steps of 128, one barrier/step, K/V dbuf LDS (r10 swizzles
// per 64-half), sP per wave, grid 1024 XCD decode, (256,4).
// ---------------------------------------------------------------------------
__global__ __launch_bounds__(256, 4) void attn_mfma(const u16* __restrict__ qt,
                                                    const u16* __restrict__ kt,
                                                    const u16* __restrict__ vt,
                                                    const u16* __restrict__ relL,
                                                    u16* __restrict__ aout) {
  __shared__ __align__(16) u16 sK[2][4096];      // [buf][2half x 32r x 8slot x 8] 16KB
  __shared__ __align__(16) u16 sV[2][4096];      // [buf][2half x 32d x 8slot x 8] 16KB
  __shared__ __align__(16) u16 sP[4][2048];      // per-wave [2half][16][8slot][8] 16KB

  const int t  = threadIdx.x;
  const int w  = t >> 6, l = t & 63, g = l >> 4, ln = l & 15;
  const int bid = blockIdx.x;
  const int xcd = bid & 7, sl = bid >> 3;   // sl 0..127
  const int b   = sl & 3;
  const int i0  = ((sl >> 2) & 15) << 6;
  const int h   = (xcd << 1) | (sl >> 6);
  const int iw  = w;                        // i-segment (16 rows)

  const size_t bh = (size_t)(b * HEADS + h);

  // staging (r10 mapping per 64-wide half): thread t stages chunk t of each
  // half. c=t -> r=c>>3, slot=c&7; sources pre-swizzled.
  const int sc_r  = t >> 3;
  const int sc_kc = (t & 7) ^ (sc_r & 7) ^ ((sc_r >> 3) & 1);
  const int sc_vc = (t & 7) ^ (sc_r & 7);
  const u16* ksrc = kt + (bh * NPIX + ((sc_r << 1) | (sc_kc >> 2))) * DH +
                    ((sc_kc & 3) << 3);
  const u16* vsrc = vt + (bh * DH + sc_r) * NPIX + (sc_vc << 3);
  char* kdst = (char*)&sK[0][0] + (w << 10);
  char* vdst = (char*)&sV[0][0] + (w << 10);

  // step s covers j in [s*128, s*128+128); half hh at +hh*64.
#define STAGE(s_, p_) do {                                                  \
    gl_lds16(ksrc + (size_t)(s_) * 4096,        kdst + (p_) * 8192);        \
    gl_lds16(ksrc + (size_t)(s_) * 4096 + 2048, kdst + (p_) * 8192 + 4096); \
    gl_lds16(vsrc + (size_t)(s_) * 128,         vdst + (p_) * 8192);        \
    gl_lds16(vsrc + (size_t)(s_) * 128 + 64,    vdst + (p_) * 8192 + 4096); \
  } while (0)

  STAGE(0, 0);

  // Q fragment (pre-scaled by scale*log2e): lane -> row i0+16*iw+ln, k=8g..+8
  bf16x8 qf = *reinterpret_cast<const bf16x8*>(
      qt + (bh * NPIX + i0 + (iw << 4) + ln) * DH + (g << 3));

  // relL (bf16, *log2e): rows i0+16iw+4g+v, cols s*128 + hh*64 + 4ln + (0..3)
  const u16* relp = relL + ((size_t)h * NPIX + i0 + (iw << 4) + (g << 2)) * NPIX +
                    (ln << 2);

  f32x4 vzero = {0.f, 0.f, 0.f, 0.f};
  f32x4 accO[2] = {vzero, vzero};
  f32x4 l_lane = vzero;

  u16* sPw = &sP[w][0];

  for (int s = 0; s < 8; ++s) {
    const int p = s & 1;
    __syncthreads();                        // buf p staged; buf p^1 free
    if (s < 7) STAGE(s + 1, p ^ 1);

    // rel loads for this step (bf16x4 as uint2; expanded after QK)
    uint2 relq[2][4];
#pragma unroll
    for (int hh = 0; hh < 2; ++hh)
#pragma unroll
      for (int v = 0; v < 4; ++v)
        relq[hh][v] = *reinterpret_cast<const uint2*>(
            relp + (size_t)v * NPIX + (s << 7) + (hh << 6));

    const u16* Kb = &sK[p][0];
    const u16* Vb = &sV[p][0];

    // ---- S' = Q'^T K: 8 fragments; frag (hh,q) covers j = 64hh + 4ln + q ----
    f32x4 sfr[8];
    __builtin_amdgcn_s_setprio(1);
#pragma unroll
    for (int jj = 0; jj < 8; ++jj) {
      const int hh = jj >> 2, q = jj & 3;
      const int r  = (ln << 1) + (q >> 1);
      const int ks = ((((q & 1) << 2) | g) ^ (r & 7)) ^ ((r >> 3) & 1);
      bf16x8 kf = *reinterpret_cast<const bf16x8*>(Kb + (hh << 11) + r * 64 + ks * 8);
      sfr[jj] = __builtin_amdgcn_mfma_f32_16x16x32_bf16(qf, kf, vzero, 0, 0, 0);
    }
    __builtin_amdgcn_s_setprio(0);

    // ---- P = exp2(S' + relL); swizzled b64 write per row per half ----
#pragma unroll
    for (int v = 0; v < 4; ++v) {
      const int rw = (g << 2) + v;
      const int pwoff = rw * 64 + ((((ln >> 1) ^ (rw & 7)) << 3) | ((ln & 1) << 2));
      {
        const uint2 rq = relq[0][v];
        float r0 = __uint_as_float((rq.x & 0xffffu) << 16);
        float r1 = __uint_as_float(rq.x & 0xffff0000u);
        float r2 = __uint_as_float((rq.y & 0xffffu) << 16);
        float r3 = __uint_as_float(rq.y & 0xffff0000u);
        float p0 = EXP2(r0 + sfr[0][v]);
        float p1 = EXP2(r1 + sfr[1][v]);
        float p2 = EXP2(r2 + sfr[2][v]);
        float p3 = EXP2(r3 + sfr[3][v]);
        l_lane[v] += (p0 + p1) + (p2 + p3);
        bf16x4 pk;
        pk[0] = (__bf16)p0; pk[1] = (__bf16)p1; pk[2] = (__bf16)p2; pk[3] = (__bf16)p3;
        *reinterpret_cast<bf16x4*>(sPw + pwoff) = pk;
      }
      {
        const uint2 rq = relq[1][v];
        float r0 = __uint_as_float((rq.x & 0xffffu) << 16);
        float r1 = __uint_as_float(rq.x & 0xffff0000u);
        float r2 = __uint_as_float((rq.y & 0xffffu) << 16);
        float r3 = __uint_as_float(rq.y & 0xffff0000u);
        float p4 = EXP2(r0 + sfr[4][v]);
        float p5 = EXP2(r1 + sfr[5][v]);
        float p6 = EXP2(r2 + sfr[6][v]);
        float p7 = EXP2(r3 + sfr[7][v]);
        l_lane[v] += (p4 + p5) + (p6 + p7);
        bf16x4 pk2;
        pk2[0] = (__bf16)p4; pk2[1] = (__bf16)p5; pk2[2] = (__bf16)p6; pk2[3] = (__bf16)p7;
        *reinterpret_cast<bf16x4*>(sPw + 1024 + pwoff) = pk2;
      }
    }

    // ---- PV: 4 k-chunks of 32 (c: hh=c>>1, kc2=c&1) x 2 d-halves ----
    __builtin_amdgcn_s_setprio(1);
#pragma unroll
    for (int c = 0; c < 4; ++c) {
      const int hh = c >> 1, kc2 = c & 1;
      const int lc = (kc2 << 2) | g;
      bf16x8 pa = *reinterpret_cast<const bf16x8*>(
          sPw + (hh << 10) + ln * 64 + ((lc ^ (ln & 7)) << 3));
#pragma unroll
      for (int dc = 0; dc < 2; ++dc) {
        const int d  = (dc << 4) + ln;
        const int vs = lc ^ (d & 7);
        bf16x8 vf = *reinterpret_cast<const bf16x8*>(Vb + (hh << 11) + d * 64 + vs * 8);
        accO[dc] = __builtin_amdgcn_mfma_f32_16x16x32_bf16(pa, vf, accO[dc], 0, 0, 0);
      }
    }
    __builtin_amdgcn_s_setprio(0);
  }
#undef STAGE

  // ---- epilogue: shuffle-reduce l, divide, bf16 write [b][n][c] ----
#pragma unroll
  for (int v = 0; v < 4; ++v) {
    float ls = l_lane[v];
    ls += __shfl_xor(ls, 1);
    ls += __shfl_xor(ls, 2);
    ls += __shfl_xor(ls, 4);
    ls += __shfl_xor(ls, 8);
    const float inv = 1.f / ls;
    const size_t row = (size_t)b * NPIX + i0 + (iw << 4) + (g << 2) + v;
    aout[row * DATTN + (h << 5) + ln]      = f2bf(accO[0][v] * inv);
    aout[row * DATTN + (h << 5) + 16 + ln] = f2bf(accO[1][v] * inv);
  }
}

// ---------------------------------------------------------------------------
// Proj GEMM (MFMA): out[b][o][n] = sum_k Wp[o,k] * A[b][n][k] + bias[o], f32 out.
// ---------------------------------------------------------------------------
__global__ __launch_bounds__(256) void gemm_proj_mfma(const u16* __restrict__ wp,
                                                      const u16* __restrict__ at,
                                                      const float* __restrict__ bias,
                                                      float* __restrict__ out) {
  __shared__ __align__(16) u16 sA[64 * 64];
  __shared__ __align__(16) u16 sB[128 * 64];
  const int t  = threadIdx.x;
  const int w  = t >> 6, l = t & 63, g = l >> 4, ln = l & 15;
  const int n0 = blockIdx.x * 128;
  const int o0 = blockIdx.y * 64;
  const int b  = blockIdx.z;
  const int wm = w >> 1, wn = w & 1;

  const u16* wbase = wp + (size_t)o0 * DATTN;
  const u16* abase = at + ((size_t)b * NPIX + n0) * DATTN;

  f32x4 acc[2][4];
#pragma unroll
  for (int mi = 0; mi < 2; ++mi)
#pragma unroll
    for (int ni = 0; ni < 4; ++ni) acc[mi][ni] = {0.f, 0.f, 0.f, 0.f};

  for (int k0 = 0; k0 < DATTN; k0 += 64) {
#pragma unroll
    for (int i = 0; i < 2; ++i) {
      int chunk = i * 256 + (w << 6) + l;
      gl_lds16(wbase + ((size_t)(chunk >> 3)) * DATTN + k0 + ((chunk & 7) << 3),
               (char*)sA + i * 4096 + (w << 10));
    }
#pragma unroll
    for (int i = 0; i < 4; ++i) {
      int chunk = i * 256 + (w << 6) + l;
      gl_lds16(abase + ((size_t)(chunk >> 3)) * DATTN + k0 + ((chunk & 7) << 3),
               (char*)sB + i * 4096 + (w << 10));
    }
    __syncthreads();
#pragma unroll
    for (int kk = 0; kk < 64; kk += 32) {
      bf16x8 af[2], bfr[4];
#pragma unroll
      for (int mi = 0; mi < 2; ++mi)
        af[mi] = *reinterpret_cast<const bf16x8*>(&sA[((wm << 5) + (mi << 4) + ln) * 64 + kk + (g << 3)]);
#pragma unroll
      for (int ni = 0; ni < 4; ++ni)
        bfr[ni] = *reinterpret_cast<const bf16x8*>(&sB[((wn << 6) + (ni << 4) + ln) * 64 + kk + (g << 3)]);
#pragma unroll
      for (int mi = 0; mi < 2; ++mi)
#pragma unroll
        for (int ni = 0; ni < 4; ++ni)
          acc[mi][ni] = __builtin_amdgcn_mfma_f32_16x16x32_bf16(af[mi], bfr[ni], acc[mi][ni], 0, 0, 0);
    }
    __syncthreads();
  }

#pragma unroll
  for (int mi = 0; mi < 2; ++mi) {
    const int o = o0 + (wm << 5) + (mi << 4) + (g << 2);
    const float b0 = bias[o], b1 = bias[o + 1], b2 = bias[o + 2], b3 = bias[o + 3];
#pragma unroll
    for (int ni = 0; ni < 4; ++ni) {
      const int n = n0 + (wn << 6) + (ni << 4) + ln;
      float* op = &out[((size_t)b * DATTN + o) * NPIX + n];
      op[0]        = acc[mi][ni][0] + b0;
      op[NPIX]     = acc[mi][ni][1] + b1;
      op[2 * NPIX] = acc[mi][ni][2] + b2;
      op[3 * NPIX] = acc[mi][ni][3] + b3;
    }
  }
}

extern "C" void kernel_launch(void* const* d_in, const int* in_sizes, int n_in,
                              void* d_out, int out_size, void* d_ws, size_t ws_size,
                              hipStream_t stream) {
  (void)in_sizes; (void)n_in; (void)out_size; (void)ws_size;
  const float* x      = (const float*)d_in[0];
  const float* w_qkv  = (const float*)d_in[1];
  const float* b_qkv  = (const float*)d_in[2];
  const float* w_proj = (const float*)d_in[3];
  const float* b_proj = (const float*)d_in[4];
  const float* rel    = (const float*)d_in[5];
  float* out = (float*)d_out;

  u16* xt    = (u16*)d_ws;                                   // 4 MB
  u16* wq_bf = xt + (size_t)BATCH * NPIX * CIN;              // 1.5 MB
  u16* wp_bf = wq_bf + (size_t)O_QKV * CIN;                  // 0.5 MB
  u16* qt    = wp_bf + (size_t)DATTN * DATTN;                // 4 MB
  u16* kt    = qt + (size_t)BATCH * HEADS * NPIX * DH;       // 4 MB
  u16* vt    = kt + (size_t)BATCH * HEADS * NPIX * DH;       // 4 MB
  u16* aout  = vt + (size_t)BATCH * HEADS * NPIX * DH;       // 4 MB
  u16* relL  = aout + (size_t)BATCH * NPIX * DATTN;          // 33.5 MB

  prep_fused<<<1536, 256, 0, stream>>>(x, w_qkv, w_proj, xt, wq_bf, wp_bf);
  gemm_qkv_mfma<<<dim3(40, HEADS, BATCH), 256, 0, stream>>>(wq_bf, xt, b_qkv, rel,
                                                            qt, kt, vt, relL);
  attn_mfma<<<1024, 256, 0, stream>>>(qt, kt, vt, relL, aout);
  gemm_proj_mfma<<<dim3(NPIX / 128, DATTN / 64, BATCH), 256, 0, stream>>>(wp_bf, aout, b_proj, out);
}

// Round 20
// 62.742 us; speedup vs baseline: 1.3042x; 1.2542x over previous
//
#include <hip/hip_runtime.h>
#include <cstdint>
#include <cstddef>

#define BATCH 4
#define CIN   512
#define NPIX  1024
#define HEADS 16
#define DH    32
#define DATTN 512
#define O_QKV 1536

typedef unsigned short u16;
typedef __bf16 bf16x4 __attribute__((ext_vector_type(4)));
typedef __bf16 bf16x8 __attribute__((ext_vector_type(8)));
typedef float  f32x4  __attribute__((ext_vector_type(4)));

typedef const __attribute__((address_space(1))) void g1_t;
typedef __attribute__((address_space(3))) void l3_t;

#if defined(__has_builtin)
#if __has_builtin(__builtin_amdgcn_exp2f)
#define EXP2(x) __builtin_amdgcn_exp2f(x)
#endif
#endif
#ifndef EXP2
#define EXP2(x) __expf((x) * 0.6931471805599453f)
#endif

__device__ __forceinline__ u16 f2bf(float f) {
  unsigned u = __float_as_uint(f);
  u += 0x7fffu + ((u >> 16) & 1u);
  return (u16)(u >> 16);
}

// async global->LDS, 16B per lane; lp must be wave-uniform (HW: base + lane*16)
__device__ __forceinline__ void gl_lds16(const void* gp, void* lp) {
  __builtin_amdgcn_global_load_lds((g1_t*)gp, (l3_t*)lp, 16, 0, 0);
}

// ---------------------------------------------------------------------------
// prep_fused: blocks 0..511 = x [B][C][N] f32 -> xt [B][N][C] bf16 (LDS
// transpose); blocks 512..1535 = w_qkv + w_proj f32 -> bf16. One launch.
// ---------------------------------------------------------------------------
__global__ __launch_bounds__(256) void prep_fused(const float* __restrict__ x,
                                                  const float* __restrict__ w1,
                                                  const float* __restrict__ w2,
                                                  u16* __restrict__ xt,
                                                  u16* __restrict__ o1,
                                                  u16* __restrict__ o2) {
  const int t = threadIdx.x;
  if (blockIdx.x < 512) {
    __shared__ float sT[64][65];
    const int q  = blockIdx.x;
    const int n0 = (q & 15) << 6;
    const int c0 = ((q >> 4) & 7) << 6;
    const int b  = q >> 7;
    const float* xb = x + ((size_t)b * CIN + c0) * NPIX + n0;
#pragma unroll
    for (int i = 0; i < 4; ++i) {
      int r   = i * 16 + (t >> 4);
      int col = (t & 15) << 2;
      float4 v = *reinterpret_cast<const float4*>(&xb[(size_t)r * NPIX + col]);
      sT[r][col + 0] = v.x; sT[r][col + 1] = v.y;
      sT[r][col + 2] = v.z; sT[r][col + 3] = v.w;
    }
    __syncthreads();
#pragma unroll
    for (int i = 0; i < 2; ++i) {
      int nl = t >> 2;
      int ch = (t & 3) + (i << 2);
      u16 tmp[8];
#pragma unroll
      for (int e = 0; e < 8; ++e) tmp[e] = f2bf(sT[(ch << 3) + e][nl]);
      *reinterpret_cast<uint4*>(&xt[((size_t)b * NPIX + n0 + nl) * CIN + c0 + (ch << 3)]) =
          *reinterpret_cast<uint4*>(tmp);
    }
  } else {
    const int idx = (blockIdx.x - 512) * 256 + t;   // float4 index
    const int n1 = (O_QKV * CIN) >> 2;              // 196608
    float4 v = (idx < n1) ? reinterpret_cast<const float4*>(w1)[idx]
                          : reinterpret_cast<const float4*>(w2)[idx - n1];
    uint2 pk = make_uint2((unsigned)f2bf(v.x) | ((unsigned)f2bf(v.y) << 16),
                          (unsigned)f2bf(v.z) | ((unsigned)f2bf(v.w) << 16));
    if (idx < n1) reinterpret_cast<uint2*>(o1)[idx] = pk;
    else          reinterpret_cast<uint2*>(o2)[idx - n1] = pk;
  }
}

// ---------------------------------------------------------------------------
// QKV GEMM (MFMA): M-tile=96 (one head), N-tile=128, BK=64, 4 waves.
// Epilogue: +bias, bf16; q PRE-SCALED by scale*log2e (attn uses exp2 domain).
// qt/kt [b][h][n][32], vt [b][h][d][n].
// ---------------------------------------------------------------------------
__global__ __launch_bounds__(256) void gemm_qkv_mfma(const u16* __restrict__ wq,
                                                     const u16* __restrict__ xt,
                                                     const float* __restrict__ bias,
                                                     u16* __restrict__ qt,
                                                     u16* __restrict__ kt,
                                                     u16* __restrict__ vt) {
  __shared__ __align__(16) u16 sA[96 * 64];
  __shared__ __align__(16) u16 sB[128 * 64];
  const int t  = threadIdx.x;
  const int w  = t >> 6, l = t & 63, g = l >> 4, ln = l & 15;
  const int n0 = blockIdx.x * 128;
  const int h  = blockIdx.y;
  const int b  = blockIdx.z;
  const int wm = w >> 1, wn = w & 1;

  const u16* wbase = wq + (size_t)h * 96 * CIN;
  const u16* xbase = xt + ((size_t)b * NPIX + n0) * CIN;

  f32x4 acc[3][4];
#pragma unroll
  for (int mi = 0; mi < 3; ++mi)
#pragma unroll
    for (int ni = 0; ni < 4; ++ni) acc[mi][ni] = {0.f, 0.f, 0.f, 0.f};

  for (int k0 = 0; k0 < CIN; k0 += 64) {
#pragma unroll
    for (int i = 0; i < 3; ++i) {
      int chunk = i * 256 + (w << 6) + l;
      gl_lds16(wbase + ((size_t)(chunk >> 3)) * CIN + k0 + ((chunk & 7) << 3),
               (char*)sA + i * 4096 + (w << 10));
    }
#pragma unroll
    for (int i = 0; i < 4; ++i) {
      int chunk = i * 256 + (w << 6) + l;
      gl_lds16(xbase + ((size_t)(chunk >> 3)) * CIN + k0 + ((chunk & 7) << 3),
               (char*)sB + i * 4096 + (w << 10));
    }
    __syncthreads();
#pragma unroll
    for (int kk = 0; kk < 64; kk += 32) {
      bf16x8 af[3], bfr[4];
#pragma unroll
      for (int mi = 0; mi < 3; ++mi)
        af[mi] = *reinterpret_cast<const bf16x8*>(&sA[(48 * wm + 16 * mi + ln) * 64 + kk + (g << 3)]);
#pragma unroll
      for (int ni = 0; ni < 4; ++ni)
        bfr[ni] = *reinterpret_cast<const bf16x8*>(&sB[((wn << 6) + (ni << 4) + ln) * 64 + kk + (g << 3)]);
#pragma unroll
      for (int mi = 0; mi < 3; ++mi)
#pragma unroll
        for (int ni = 0; ni < 4; ++ni)
          acc[mi][ni] = __builtin_amdgcn_mfma_f32_16x16x32_bf16(af[mi], bfr[ni], acc[mi][ni], 0, 0, 0);
    }
    __syncthreads();
  }

  const float QSC = 0.17677669529663687f * 1.4426950408889634f;  // scale*log2e
  const float* bh = bias + h * 96;
#pragma unroll
  for (int mi = 0; mi < 3; ++mi) {
    const int sec = 48 * wm + 16 * mi;
    const int rb  = sec + (g << 2);
    const float b0 = bh[rb + 0], b1 = bh[rb + 1], b2 = bh[rb + 2], b3 = bh[rb + 3];
#pragma unroll
    for (int ni = 0; ni < 4; ++ni) {
      const int n = n0 + (wn << 6) + (ni << 4) + ln;
      f32x4 a = acc[mi][ni];
      float v0 = a[0] + b0, v1 = a[1] + b1, v2 = a[2] + b2, v3 = a[3] + b3;
      if (sec < 32) { v0 *= QSC; v1 *= QSC; v2 *= QSC; v3 *= QSC; }
      u16 e0 = f2bf(v0), e1 = f2bf(v1), e2 = f2bf(v2), e3 = f2bf(v3);
      if (sec < 32) {
        const int d = sec + (g << 2);
        uint2 pk = make_uint2((unsigned)e0 | ((unsigned)e1 << 16),
                              (unsigned)e2 | ((unsigned)e3 << 16));
        *reinterpret_cast<uint2*>(&qt[(((size_t)(b * HEADS + h)) * NPIX + n) * DH + d]) = pk;
      } else if (sec < 64) {
        const int d = sec - 32 + (g << 2);
        uint2 pk = make_uint2((unsigned)e0 | ((unsigned)e1 << 16),
                              (unsigned)e2 | ((unsigned)e3 << 16));
        *reinterpret_cast<uint2*>(&kt[(((size_t)(b * HEADS + h)) * NPIX + n) * DH + d]) = pk;
      } else {
        const int d = sec - 64 + (g << 2);
        u16* vp = &vt[(((size_t)(b * HEADS + h)) * DH + d) * NPIX + n];
        vp[0] = e0; vp[NPIX] = e1; vp[2 * NPIX] = e2; vp[3 * NPIX] = e3;
      }
    }
  }
}

// ---------------------------------------------------------------------------
// MFMA flash attention v20 -- IN-WAVE BATCH PAIR (register-level rel reuse).
// r18 confirmed attn time tracks the rel L2/L3 stream (256MB f32 -> 43us;
// 128MB bf16 -> 27us) but materializing bf16 rel cost ~16-29us. This version
// halves the F32 stream with ZERO conversion: each wave processes TWO batches
// (bw = bp*2 + b2), loading rel once per step and using it for both batches'
// exp. All tile math is r10-verbatim (verified); sP reused per batch
// sequentially (same-wave DS in-order, r12-verified pattern).
// Block 256 thr / 4 waves (iw = 16 rows each), 16 j-steps of 64, one
// __syncthreads/step. LDS 40KB. Grid 512: xcd=bid&7, sl=bid>>3; bp=sl&1
// (bp-siblings bid-dist-8 -> same XCD, adjacent -> rel L2 reuse, r8-verified
// FETCH 39MB), i0=((sl>>1)&15)<<6, h=(xcd<<1)|(sl>>5).
// K LDS per (buf,b2): [32 packed rows r=j>>1][8 slots 16B], slot^=(r&7)^((r>>3)&1).
// V LDS per (buf,b2): [32 d][8 slots 16B], slot^=(d&7).
// sP per wave: [16 rows][8 slots 16B], slot^=(row&7); b64 half-slot writes.
// ---------------------------------------------------------------------------
__global__ __launch_bounds__(256, 2) void attn_mfma(const u16* __restrict__ qt,
                                                    const u16* __restrict__ kt,
                                                    const u16* __restrict__ vt,
                                                    const float* __restrict__ rel,
                                                    u16* __restrict__ aout) {
  __shared__ __align__(16) u16 sK[2][2][2048];   // [buf][b2][32r][8slot][8] 16KB
  __shared__ __align__(16) u16 sV[2][2][2048];   // [buf][b2][32d][8slot][8] 16KB
  __shared__ __align__(16) u16 sP[4][1024];      // per-wave [16][8slot][8]   8KB

  const int t  = threadIdx.x;
  const int w  = t >> 6, l = t & 63, g = l >> 4, ln = l & 15;
  const int bid = blockIdx.x;
  const int xcd = bid & 7, sl = bid >> 3;   // sl 0..63
  const int bp  = sl & 1;                   // batch pair
  const int i0  = ((sl >> 1) & 15) << 6;
  const int h   = (xcd << 1) | (sl >> 5);
  const int iw  = w;                        // i-segment (16 rows)

  const size_t bh0 = (size_t)((bp * 2 + 0) * HEADS + h);
  const size_t bh1 = (size_t)((bp * 2 + 1) * HEADS + h);

  // staging (r10 mapping, one issue per local batch): issue i stages batch i.
  // c = i*256 + t -> r = t>>3, slot = t&7 (identical per-issue to r10).
  const int sc_r  = t >> 3;
  const int sc_kc = (t & 7) ^ (sc_r & 7) ^ ((sc_r >> 3) & 1);  // K logical chunk
  const int sc_vc = (t & 7) ^ (sc_r & 7);                      // V logical chunk
  const size_t kro = ((size_t)((sc_r << 1) | (sc_kc >> 2))) * DH + ((sc_kc & 3) << 3);
  const u16* ksrc0 = kt + bh0 * NPIX * DH + kro;
  const u16* ksrc1 = kt + bh1 * NPIX * DH + kro;
  const u16* vsrc0 = vt + (bh0 * DH + sc_r) * NPIX + (sc_vc << 3);
  const u16* vsrc1 = vt + (bh1 * DH + sc_r) * NPIX + (sc_vc << 3);
  char* kBase = (char*)&sK[0][0][0] + (w << 10);   // + p*8192 + i*4096
  char* vBase = (char*)&sV[0][0][0] + (w << 10);

#define STAGE(s_, p_) do {                                               \
    gl_lds16(ksrc0 + (size_t)(s_) * 2048, kBase + (p_) * 8192);          \
    gl_lds16(ksrc1 + (size_t)(s_) * 2048, kBase + (p_) * 8192 + 4096);   \
    gl_lds16(vsrc0 + (size_t)(s_) * 64,   vBase + (p_) * 8192);          \
    gl_lds16(vsrc1 + (size_t)(s_) * 64,   vBase + (p_) * 8192 + 4096);   \
  } while (0)

  STAGE(0, 0);

  // Q fragments (pre-scaled by scale*log2e): lane -> row i0+16*iw+ln, k=8g..
  bf16x8 qf0 = *reinterpret_cast<const bf16x8*>(
      qt + (bh0 * NPIX + i0 + (iw << 4) + ln) * DH + (g << 3));
  bf16x8 qf1 = *reinterpret_cast<const bf16x8*>(
      qt + (bh1 * NPIX + i0 + (iw << 4) + ln) * DH + (g << 3));

  // rel: rows i0+16iw+4g+v, cols s*64 + 4ln + (0..3) -- loaded ONCE, used x2
  const float* relp = rel + ((size_t)h * NPIX + i0 + (iw << 4) + (g << 2)) * NPIX +
                      (ln << 2);
  f32x4 relA4[4], relB4[4];
#pragma unroll
  for (int v = 0; v < 4; ++v)
    relA4[v] = *reinterpret_cast<const f32x4*>(relp + (size_t)v * NPIX);

  f32x4 vzero = {0.f, 0.f, 0.f, 0.f};
  f32x4 accO0[2] = {vzero, vzero};
  f32x4 accO1[2] = {vzero, vzero};
  f32x4 l_lane0 = vzero, l_lane1 = vzero;

  u16* sPw = &sP[w][0];
  const float LOG2E = 1.4426950408889634f;

  for (int s = 0; s < 16; ++s) {
    const int p = s & 1;
    __syncthreads();                        // buf p staged; buf p^1 free
    if (s < 15) {
      STAGE(s + 1, p ^ 1);
#pragma unroll
      for (int v = 0; v < 4; ++v)
        relB4[v] = *reinterpret_cast<const f32x4*>(relp + (size_t)v * NPIX + ((s + 1) << 6));
    }

#pragma unroll
    for (int b2 = 0; b2 < 2; ++b2) {
      const u16* Kb = &sK[p][b2][0];
      const u16* Vb = &sV[p][b2][0];
      const bf16x8 qf = b2 ? qf1 : qf0;

      // ---- S' = Q'^T K: fragment jj covers cols j = 4*ln + jj ----
      f32x4 sfr[4];
      __builtin_amdgcn_s_setprio(1);
#pragma unroll
      for (int jj = 0; jj < 4; ++jj) {
        const int r  = (ln << 1) + (jj >> 1);
        const int ks = ((((jj & 1) << 2) | g) ^ (r & 7)) ^ ((r >> 3) & 1);
        bf16x8 kf = *reinterpret_cast<const bf16x8*>(Kb + r * 64 + ks * 8);
        sfr[jj] = __builtin_amdgcn_mfma_f32_16x16x32_bf16(qf, kf, vzero, 0, 0, 0);
      }
      __builtin_amdgcn_s_setprio(0);

      // ---- P = exp2(S' + rel*log2e); swizzled b64 write per row ----
#pragma unroll
      for (int v = 0; v < 4; ++v) {
        float p0 = EXP2(fmaf(relA4[v][0], LOG2E, sfr[0][v]));
        float p1 = EXP2(fmaf(relA4[v][1], LOG2E, sfr[1][v]));
        float p2 = EXP2(fmaf(relA4[v][2], LOG2E, sfr[2][v]));
        float p3 = EXP2(fmaf(relA4[v][3], LOG2E, sfr[3][v]));
        if (b2) l_lane1[v] += (p0 + p1) + (p2 + p3);
        else    l_lane0[v] += (p0 + p1) + (p2 + p3);
        bf16x4 pk;
        pk[0] = (__bf16)p0; pk[1] = (__bf16)p1; pk[2] = (__bf16)p2; pk[3] = (__bf16)p3;
        const int rw = (g << 2) + v;
        *reinterpret_cast<bf16x4*>(
            sPw + rw * 64 + ((((ln >> 1) ^ (rw & 7)) << 3) | ((ln & 1) << 2))) = pk;
      }

      // ---- PV: acc[dc] += P(kc) x V(kc,dc) ----
      __builtin_amdgcn_s_setprio(1);
#pragma unroll
      for (int kc = 0; kc < 2; ++kc) {
        const int lc = (kc << 2) | g;
        bf16x8 pa = *reinterpret_cast<const bf16x8*>(sPw + ln * 64 + ((lc ^ (ln & 7)) << 3));
#pragma unroll
        for (int dc = 0; dc < 2; ++dc) {
          const int d  = (dc << 4) + ln;
          const int vs = lc ^ (d & 7);
          bf16x8 vf = *reinterpret_cast<const bf16x8*>(Vb + d * 64 + vs * 8);
          if (b2) accO1[dc] = __builtin_amdgcn_mfma_f32_16x16x32_bf16(pa, vf, accO1[dc], 0, 0, 0);
          else    accO0[dc] = __builtin_amdgcn_mfma_f32_16x16x32_bf16(pa, vf, accO0[dc], 0, 0, 0);
        }
      }
      __builtin_amdgcn_s_setprio(0);
    }

    if (s < 15) {
#pragma unroll
      for (int v = 0; v < 4; ++v) relA4[v] = relB4[v];
    }
  }
#undef STAGE

  // ---- epilogue: shuffle-reduce l, divide, bf16 write [b][n][c], x2 ----
#pragma unroll
  for (int v = 0; v < 4; ++v) {
    float ls = l_lane0[v];
    ls += __shfl_xor(ls, 1);
    ls += __shfl_xor(ls, 2);
    ls += __shfl_xor(ls, 4);
    ls += __shfl_xor(ls, 8);
    const float inv = 1.f / ls;
    const size_t row = (size_t)(bp * 2 + 0) * NPIX + i0 + (iw << 4) + (g << 2) + v;
    aout[row * DATTN + (h << 5) + ln]      = f2bf(accO0[0][v] * inv);
    aout[row * DATTN + (h << 5) + 16 + ln] = f2bf(accO0[1][v] * inv);
  }
#pragma unroll
  for (int v = 0; v < 4; ++v) {
    float ls = l_lane1[v];
    ls += __shfl_xor(ls, 1);
    ls += __shfl_xor(ls, 2);
    ls += __shfl_xor(ls, 4);
    ls += __shfl_xor(ls, 8);
    const float inv = 1.f / ls;
    const size_t row = (size_t)(bp * 2 + 1) * NPIX + i0 + (iw << 4) + (g << 2) + v;
    aout[row * DATTN + (h << 5) + ln]      = f2bf(accO1[0][v] * inv);
    aout[row * DATTN + (h << 5) + 16 + ln] = f2bf(accO1[1][v] * inv);
  }
}

// ---------------------------------------------------------------------------
// Proj GEMM (MFMA): out[b][o][n] = sum_k Wp[o,k] * A[b][n][k] + bias[o], f32 out.
// ---------------------------------------------------------------------------
__global__ __launch_bounds__(256) void gemm_proj_mfma(const u16* __restrict__ wp,
                                                      const u16* __restrict__ at,
                                                      const float* __restrict__ bias,
                                                      float* __restrict__ out) {
  __shared__ __align__(16) u16 sA[64 * 64];
  __shared__ __align__(16) u16 sB[128 * 64];
  const int t  = threadIdx.x;
  const int w  = t >> 6, l = t & 63, g = l >> 4, ln = l & 15;
  const int n0 = blockIdx.x * 128;
  const int o0 = blockIdx.y * 64;
  const int b  = blockIdx.z;
  const int wm = w >> 1, wn = w & 1;

  const u16* wbase = wp + (size_t)o0 * DATTN;
  const u16* abase = at + ((size_t)b * NPIX + n0) * DATTN;

  f32x4 acc[2][4];
#pragma unroll
  for (int mi = 0; mi < 2; ++mi)
#pragma unroll
    for (int ni = 0; ni < 4; ++ni) acc[mi][ni] = {0.f, 0.f, 0.f, 0.f};

  for (int k0 = 0; k0 < DATTN; k0 += 64) {
#pragma unroll
    for (int i = 0; i < 2; ++i) {
      int chunk = i * 256 + (w << 6) + l;
      gl_lds16(wbase + ((size_t)(chunk >> 3)) * DATTN + k0 + ((chunk & 7) << 3),
               (char*)sA + i * 4096 + (w << 10));
    }
#pragma unroll
    for (int i = 0; i < 4; ++i) {
      int chunk = i * 256 + (w << 6) + l;
      gl_lds16(abase + ((size_t)(chunk >> 3)) * DATTN + k0 + ((chunk & 7) << 3),
               (char*)sB + i * 4096 + (w << 10));
    }
    __syncthreads();
#pragma unroll
    for (int kk = 0; kk < 64; kk += 32) {
      bf16x8 af[2], bfr[4];
#pragma unroll
      for (int mi = 0; mi < 2; ++mi)
        af[mi] = *reinterpret_cast<const bf16x8*>(&sA[((wm << 5) + (mi << 4) + ln) * 64 + kk + (g << 3)]);
#pragma unroll
      for (int ni = 0; ni < 4; ++ni)
        bfr[ni] = *reinterpret_cast<const bf16x8*>(&sB[((wn << 6) + (ni << 4) + ln) * 64 + kk + (g << 3)]);
#pragma unroll
      for (int mi = 0; mi < 2; ++mi)
#pragma unroll
        for (int ni = 0; ni < 4; ++ni)
          acc[mi][ni] = __builtin_amdgcn_mfma_f32_16x16x32_bf16(af[mi], bfr[ni], acc[mi][ni], 0, 0, 0);
    }
    __syncthreads();
  }

#pragma unroll
  for (int mi = 0; mi < 2; ++mi) {
    const int o = o0 + (wm << 5) + (mi << 4) + (g << 2);
    const float b0 = bias[o], b1 = bias[o + 1], b2 = bias[o + 2], b3 = bias[o + 3];
#pragma unroll
    for (int ni = 0; ni < 4; ++ni) {
      const int n = n0 + (wn << 6) + (ni << 4) + ln;
      float* op = &out[((size_t)b * DATTN + o) * NPIX + n];
      op[0]        = acc[mi][ni][0] + b0;
      op[NPIX]     = acc[mi][ni][1] + b1;
      op[2 * NPIX] = acc[mi][ni][2] + b2;
      op[3 * NPIX] = acc[mi][ni][3] + b3;
    }
  }
}

extern "C" void kernel_launch(void* const* d_in, const int* in_sizes, int n_in,
                              void* d_out, int out_size, void* d_ws, size_t ws_size,
                              hipStream_t stream) {
  (void)in_sizes; (void)n_in; (void)out_size; (void)ws_size;
  const float* x      = (const float*)d_in[0];
  const float* w_qkv  = (const float*)d_in[1];
  const float* b_qkv  = (const float*)d_in[2];
  const float* w_proj = (const float*)d_in[3];
  const float* b_proj = (const float*)d_in[4];
  const float* rel    = (const float*)d_in[5];
  float* out = (float*)d_out;

  u16* xt    = (u16*)d_ws;                                   // 4 MB
  u16* wq_bf = xt + (size_t)BATCH * NPIX * CIN;              // 1.5 MB
  u16* wp_bf = wq_bf + (size_t)O_QKV * CIN;                  // 0.5 MB
  u16* qt    = wp_bf + (size_t)DATTN * DATTN;                // 4 MB
  u16* kt    = qt + (size_t)BATCH * HEADS * NPIX * DH;       // 4 MB
  u16* vt    = kt + (size_t)BATCH * HEADS * NPIX * DH;       // 4 MB
  u16* aout  = vt + (size_t)BATCH * HEADS * NPIX * DH;       // 4 MB

  prep_fused<<<1536, 256, 0, stream>>>(x, w_qkv, w_proj, xt, wq_bf, wp_bf);
  gemm_qkv_mfma<<<dim3(NPIX / 128, HEADS, BATCH), 256, 0, stream>>>(wq_bf, xt, b_qkv, qt, kt, vt);
  attn_mfma<<<512, 256, 0, stream>>>(qt, kt, vt, rel, aout);
  gemm_proj_mfma<<<dim3(NPIX / 128, DATTN / 64, BATCH), 256, 0, stream>>>(wp_bf, aout, b_proj, out);
}